// Round 9
// baseline (609.704 us; speedup 1.0000x reference)
//
#include <hip/hip_runtime.h>

#define N_NODES 296960
#define N_EDGES 2375680
#define IN_FEATS 75
#define DIM 128
#define N_LAYERS 3
#define ECAP 4096                        // staged edge indices (16 KB, aliases both tiles)
#define KPAD 104                         // init LDS row stride (shorts)
#define KUSE 96                          // init K padded to 3x32
#define NCHUNK 128                       // CSR super-chunks
#define CHN (N_NODES / NCHUNK)           // 2320 nodes per chunk (dstLow: 12 bits; src: 19 bits)
#define ETILE 2048                       // edges per bucketing block
#define EBLKS (N_EDGES / ETILE)          // 1160
#define CVPT 5                           // scan values/thread: 512*5 = 2560 >= 2320

static_assert(N_NODES % 256 == 0, "node count divisible by 256");
static_assert(N_EDGES % ETILE == 0, "edge count divisible by tile");
static_assert(NCHUNK * CHN == N_NODES, "chunks cover nodes exactly");

typedef __attribute__((ext_vector_type(8))) short s8v;        // 8 bf16 = 4 VGPR MFMA frag
typedef __attribute__((ext_vector_type(4))) float f4v;        // 4 f32 accum frag
typedef __attribute__((ext_vector_type(4))) unsigned int u4v; // 16B nt-store unit

__device__ __forceinline__ float u2f(unsigned int x) {
    union { unsigned int u; float f; } v; v.u = x; return v.f;
}
__device__ __forceinline__ unsigned short f2b(float f) {   // f32 -> bf16 RNE
    union { float f; unsigned int u; } v; v.f = f;
    unsigned int r = v.u + 0x7fffu + ((v.u >> 16) & 1u);
    return (unsigned short)(r >> 16);
}
__device__ __forceinline__ void addbf8(f4v& a, f4v& b, uint4 q) {  // 8 bf16 -> f32 accum
    a.x += u2f(q.x << 16); a.y += u2f(q.x & 0xffff0000u);
    a.z += u2f(q.y << 16); a.w += u2f(q.y & 0xffff0000u);
    b.x += u2f(q.z << 16); b.y += u2f(q.z & 0xffff0000u);
    b.z += u2f(q.w << 16); b.w += u2f(q.w & 0xffff0000u);
}

// ================================================================ CSR build (locality-aware 2-pass sort)
__global__ void zero_i(int* __restrict__ p, int n) {
    int i = blockIdx.x * blockDim.x + threadIdx.x;
    if (i < n) p[i] = 0;
}

__global__ __launch_bounds__(256) void coarse_hist(const int* __restrict__ dst,
                                                   int* __restrict__ ccnt) {
    __shared__ int cnt[NCHUNK];
    const int tid = threadIdx.x;
    if (tid < NCHUNK) cnt[tid] = 0;
    __syncthreads();
    const int base = blockIdx.x * ETILE;
    #pragma unroll
    for (int i = 0; i < ETILE / 256; ++i) {
        const int d = dst[base + i * 256 + tid];
        atomicAdd(&cnt[d / CHN], 1);
    }
    __syncthreads();
    if (tid < NCHUNK && cnt[tid] > 0) atomicAdd(&ccnt[tid], cnt[tid]);
}

__global__ void coarse_scan(const int* __restrict__ ccnt, int* __restrict__ bucketBase) {
    __shared__ int lds[NCHUNK];
    const int tid = threadIdx.x;
    if (tid < NCHUNK) lds[tid] = ccnt[tid];
    __syncthreads();
    if (tid == 0) {
        int run = 0;
        for (int k = 0; k < NCHUNK; ++k) {
            const int v = lds[k];
            lds[k] = run;
            run += v;
        }
        bucketBase[NCHUNK] = run;
    }
    __syncthreads();
    if (tid < NCHUNK) bucketBase[tid] = lds[tid];
}

__global__ __launch_bounds__(256) void bucket_pass(
    const int* __restrict__ src, const int* __restrict__ dst,
    const int* __restrict__ bucketBase, int* __restrict__ bcur,
    unsigned int* __restrict__ bedge) {
    __shared__ int cnt[NCHUNK];
    __shared__ int cnt2[NCHUNK];
    __shared__ int basei[NCHUNK];
    const int tid = threadIdx.x;
    if (tid < NCHUNK) { cnt[tid] = 0; cnt2[tid] = 0; }
    __syncthreads();

    const int base = blockIdx.x * ETILE;
    int s8[ETILE / 256], b8[ETILE / 256], dl8[ETILE / 256];
    #pragma unroll
    for (int i = 0; i < ETILE / 256; ++i) {
        const int e = base + i * 256 + tid;
        s8[i] = src[e];
        const int d = dst[e];
        b8[i] = d / CHN;
        dl8[i] = d - b8[i] * CHN;
        atomicAdd(&cnt[b8[i]], 1);
    }
    __syncthreads();
    if (tid < NCHUNK && cnt[tid] > 0)
        basei[tid] = bucketBase[tid] + atomicAdd(&bcur[tid], cnt[tid]);
    __syncthreads();
    #pragma unroll
    for (int i = 0; i < ETILE / 256; ++i) {
        const int pos = basei[b8[i]] + atomicAdd(&cnt2[b8[i]], 1);
        bedge[pos] = ((unsigned int)dl8[i] << 19) | (unsigned int)s8[i];
    }
}

__global__ __launch_bounds__(512) void csr_pass(
    const unsigned int* __restrict__ bedge, const int* __restrict__ bucketBase,
    int* __restrict__ rowptr, int* __restrict__ eidx) {
    __shared__ int cnt[512 * CVPT];
    __shared__ int wexcl[9];
    const int tid = threadIdx.x;
    const int c = blockIdx.x;
    const int nodeBase = c * CHN;
    const int segBeg = bucketBase[c];
    const int nseg = bucketBase[c + 1] - segBeg;

    #pragma unroll
    for (int j = 0; j < CVPT; ++j) cnt[tid * CVPT + j] = 0;
    __syncthreads();

    for (int i = tid; i < nseg; i += 512)
        atomicAdd(&cnt[bedge[segBeg + i] >> 19], 1);
    __syncthreads();

    int v[CVPT];
    int s = 0;
    #pragma unroll
    for (int j = 0; j < CVPT; ++j) { v[j] = cnt[tid * CVPT + j]; s += v[j]; }
    const int lane = tid & 63, wid = tid >> 6;
    int x = s;
    #pragma unroll
    for (int st = 1; st < 64; st <<= 1) {
        const int t = __shfl_up(x, st, 64);
        if (lane >= st) x += t;
    }
    if (lane == 63) wexcl[wid + 1] = x;
    __syncthreads();
    if (tid == 0) {
        wexcl[0] = 0;
        for (int k = 1; k <= 8; ++k) wexcl[k] += wexcl[k - 1];
    }
    __syncthreads();
    int run = segBeg + wexcl[wid] + (x - s);
    #pragma unroll
    for (int j = 0; j < CVPT; ++j) { cnt[tid * CVPT + j] = run; run += v[j]; }
    __syncthreads();

    for (int n = tid; n < CHN; n += 512)
        rowptr[nodeBase + n] = cnt[n];
    if (c == NCHUNK - 1 && tid == 0) rowptr[N_NODES] = N_EDGES;
    __syncthreads();

    for (int i = tid; i < nseg; i += 512) {
        const unsigned int p = bedge[segBeg + i];
        const int pos = atomicAdd(&cnt[p >> 19], 1);
        eidx[pos] = (int)(p & 0x7FFFFu);
    }
}

// ================================================================ weight transpose+cvt
__global__ void wcvt(const float* __restrict__ Wgc, const float* __restrict__ Wres,
                     unsigned short* __restrict__ Wt) {
    const int m = blockIdx.x >> 6;
    const int idx = (blockIdx.x & 63) * 256 + threadIdx.x;
    const float* src = (m < 3) ? (Wgc + m * 16384) : (Wres + (m - 3) * 16384);
    const int n = idx >> 7, k = idx & 127;
    Wt[m * 16384 + idx] = f2b(src[k * 128 + n]);
}

__global__ void wcvt_init(const float* __restrict__ Wi, unsigned short* __restrict__ WtI) {
    int idx = blockIdx.x * 256 + threadIdx.x;
    if (idx >= 128 * KUSE) return;
    int n = idx / KUSE, k = idx - n * KUSE;
    WtI[idx] = (k < IN_FEATS) ? f2b(Wi[(size_t)k * DIM + n]) : (unsigned short)0;
}

// ================================================================ h0 = X @ W_init via MFMA -> bf16 (nt writes, LDS transpose)
__global__ __launch_bounds__(256) void init_mfma(const float* __restrict__ X,
                                                 const unsigned short* __restrict__ WtI,
                                                 unsigned short* __restrict__ H) {
    __shared__ short sX[32][KPAD];
    __shared__ short sOut[32][DIM];   // 8 KB transpose staging
    const int tid = threadIdx.x;
    const int rowBase = blockIdx.x * 32;

    for (int idx = tid; idx < 32 * IN_FEATS; idx += 256) {
        const int row = idx / IN_FEATS;
        const int k = idx - row * IN_FEATS;
        sX[row][k] = (short)f2b(X[(size_t)rowBase * IN_FEATS + idx]);
    }
    #pragma unroll
    for (int i = 0; i < 4; ++i) {
        const int idx = tid + i * 256;
        const int row = idx >> 5;
        const int col = IN_FEATS + (idx & 31);
        if (col < KPAD) sX[row][col] = 0;
    }
    __syncthreads();

    const int w = tid >> 6;
    const int l = tid & 63;
    const int lr = l & 15;
    const int lk = l >> 4;

    f4v acc[2][2] = {{{0.f,0.f,0.f,0.f},{0.f,0.f,0.f,0.f}},{{0.f,0.f,0.f,0.f},{0.f,0.f,0.f,0.f}}};

    #pragma unroll
    for (int kb = 0; kb < 3; ++kb) {
        const int kofs = kb * 32 + lk * 8;
        s8v a[2], b[2];
        a[0] = *reinterpret_cast<const s8v*>(&sX[lr][kofs]);
        a[1] = *reinterpret_cast<const s8v*>(&sX[16 + lr][kofs]);
        #pragma unroll
        for (int ct = 0; ct < 2; ++ct) {
            const int col = w * 32 + ct * 16 + lr;
            b[ct] = *reinterpret_cast<const s8v*>(WtI + (size_t)col * KUSE + kofs);
        }
        #pragma unroll
        for (int rt = 0; rt < 2; ++rt)
            #pragma unroll
            for (int ct = 0; ct < 2; ++ct)
                acc[rt][ct] = __builtin_amdgcn_mfma_f32_16x16x32_bf16(a[rt], b[ct], acc[rt][ct], 0, 0, 0);
    }

    #pragma unroll
    for (int ct = 0; ct < 2; ++ct) {
        const int col = w * 32 + ct * 16 + lr;
        #pragma unroll
        for (int rt = 0; rt < 2; ++rt)
            #pragma unroll
            for (int r = 0; r < 4; ++r) {
                const int row = rt * 16 + lk * 4 + r;
                sOut[row][col] = (short)f2b(acc[rt][ct][r]);
            }
    }
    __syncthreads();
    #pragma unroll
    for (int i = 0; i < 2; ++i) {
        const int id = tid + i * 256;
        const int row = id >> 4;
        const int col8 = (id & 15) * 8;
        __builtin_nontemporal_store(
            *reinterpret_cast<const u4v*>(&sOut[row][col8]),
            reinterpret_cast<u4v*>(H + (size_t)(rowBase + row) * DIM + col8));
    }
}

// ================================================================ fused gather + dual MFMA GEMM
// nt stores on output; gather/own loads stay cached (L2 reuse set)
template <int LAST>
__global__ __launch_bounds__(256) void layer_mfma(
    const unsigned short* __restrict__ Hin, unsigned short* __restrict__ HoutB,
    float* __restrict__ HoutF,
    const int* __restrict__ rowptr, const int* __restrict__ eidx,
    const unsigned short* __restrict__ WgcT, const unsigned short* __restrict__ WresT,
    const float* __restrict__ bgc, const float* __restrict__ bres) {
    __shared__ short sTiles[2][32][DIM];     // [0]=agg, [1]=own : 16 KB
    int* sE = (int*)&sTiles[0][0][0];        // aliases both tiles during staging
    char* aggB = (char*)&sTiles[0][0][0];
    char* ownB = (char*)&sTiles[1][0][0];

    const int tid = threadIdx.x;
    const int rowBase = blockIdx.x * 32;

    const int blkBeg = rowptr[rowBase];
    const int blkEnd = rowptr[rowBase + 32];
    const int nE = blkEnd - blkBeg;
    const int nStage = (nE < ECAP) ? nE : ECAP;

    for (int i = tid; i < nStage; i += 256)
        sE[i] = __builtin_nontemporal_load(eidx + blkBeg + i);
    __syncthreads();

    // ---- gather: 16 groups of 16 lanes, 2 nodes/group, uint4 rows, 4-deep ----
    const int gg = tid >> 4;
    const int lane16 = tid & 15;
    const unsigned short* HinL = Hin + lane16 * 8;

    int begv[2], endv[2], rel[2];
    f4v accA[2], accB[2];
    uint4 own[2];
    int md = 0;
    #pragma unroll
    for (int ii = 0; ii < 2; ++ii) {
        const int node = rowBase + gg * 2 + ii;
        begv[ii] = rowptr[node];
        endv[ii] = rowptr[node + 1];
        rel[ii] = begv[ii] - blkBeg;
        own[ii] = *reinterpret_cast<const uint4*>(HinL + (size_t)node * DIM);
        accA[ii] = (f4v){0.f, 0.f, 0.f, 0.f};
        accB[ii] = (f4v){0.f, 0.f, 0.f, 0.f};
        const int d = endv[ii] - begv[ii];
        md = (d > md) ? d : md;
    }

    if (nE <= ECAP) {
        for (int t = 0; t < md; t += 4) {
            uint4 q[2][4];
            #pragma unroll
            for (int ii = 0; ii < 2; ++ii)
                #pragma unroll
                for (int j = 0; j < 4; ++j) {
                    q[ii][j] = make_uint4(0u, 0u, 0u, 0u);
                    const int e = begv[ii] + t + j;
                    if (e < endv[ii])
                        q[ii][j] = *reinterpret_cast<const uint4*>(
                            HinL + (size_t)sE[rel[ii] + t + j] * DIM);
                }
            #pragma unroll
            for (int ii = 0; ii < 2; ++ii)
                #pragma unroll
                for (int j = 0; j < 4; ++j)
                    addbf8(accA[ii], accB[ii], q[ii][j]);
        }
    } else {
        #pragma unroll
        for (int ii = 0; ii < 2; ++ii)
            for (int e = begv[ii]; e < endv[ii]; ++e)
                addbf8(accA[ii], accB[ii],
                       *reinterpret_cast<const uint4*>(HinL + (size_t)eidx[e] * DIM));
    }
    __syncthreads();   // sE dead

    // ---- write swizzled bf16 A-tiles ----
    #pragma unroll
    for (int ii = 0; ii < 2; ++ii) {
        const int row = gg * 2 + ii;
        const int kbyte = lane16 * 16;
        const int sw = kbyte ^ ((row & 7) << 4);
        uint4 p;
        p.x = (unsigned)f2b(accA[ii].x) | ((unsigned)f2b(accA[ii].y) << 16);
        p.y = (unsigned)f2b(accA[ii].z) | ((unsigned)f2b(accA[ii].w) << 16);
        p.z = (unsigned)f2b(accB[ii].x) | ((unsigned)f2b(accB[ii].y) << 16);
        p.w = (unsigned)f2b(accB[ii].z) | ((unsigned)f2b(accB[ii].w) << 16);
        *reinterpret_cast<uint4*>(aggB + row * 256 + sw) = p;
        *reinterpret_cast<uint4*>(ownB + row * 256 + sw) = own[ii];
    }
    __syncthreads();

    // ---- dual MFMA GEMM: wave w -> cols [w*32, w*32+32) ----
    const int w = tid >> 6;
    const int l = tid & 63;
    const int lr = l & 15;
    const int lk = l >> 4;

    f4v accG[2][2] = {{{0.f,0.f,0.f,0.f},{0.f,0.f,0.f,0.f}},{{0.f,0.f,0.f,0.f},{0.f,0.f,0.f,0.f}}};
    f4v accR[2][2] = {{{0.f,0.f,0.f,0.f},{0.f,0.f,0.f,0.f}},{{0.f,0.f,0.f,0.f},{0.f,0.f,0.f,0.f}}};

    #pragma unroll
    for (int kb = 0; kb < 4; ++kb) {
        const int kofs = kb * 32 + lk * 8;
        const int kbyte = kofs * 2;
        s8v aG[2], aO[2];
        #pragma unroll
        for (int rt = 0; rt < 2; ++rt) {
            const int row = rt * 16 + lr;
            const int byte = row * 256 + (kbyte ^ ((row & 7) << 4));
            aG[rt] = *reinterpret_cast<const s8v*>(aggB + byte);
            aO[rt] = *reinterpret_cast<const s8v*>(ownB + byte);
        }
        s8v bG[2], bR[2];
        #pragma unroll
        for (int ct = 0; ct < 2; ++ct) {
            const int col = w * 32 + ct * 16 + lr;
            const size_t off = (size_t)col * DIM + kofs;
            bG[ct] = *reinterpret_cast<const s8v*>(WgcT + off);
            bR[ct] = *reinterpret_cast<const s8v*>(WresT + off);
        }
        #pragma unroll
        for (int rt = 0; rt < 2; ++rt) {
            #pragma unroll
            for (int ct = 0; ct < 2; ++ct) {
                accG[rt][ct] = __builtin_amdgcn_mfma_f32_16x16x32_bf16(aG[rt], bG[ct], accG[rt][ct], 0, 0, 0);
                accR[rt][ct] = __builtin_amdgcn_mfma_f32_16x16x32_bf16(aO[rt], bR[ct], accR[rt][ct], 0, 0, 0);
            }
        }
    }

    if (LAST) {
        // f32 direct: 16 consecutive lanes x 4B = full 64B lines; nt store
        #pragma unroll
        for (int ct = 0; ct < 2; ++ct) {
            const int col = w * 32 + ct * 16 + lr;
            const float bg = bgc[col];
            const float br = bres[col];
            #pragma unroll
            for (int rt = 0; rt < 2; ++rt)
                #pragma unroll
                for (int r = 0; r < 4; ++r) {
                    const int row = rowBase + rt * 16 + lk * 4 + r;
                    __builtin_nontemporal_store(
                        fmaxf(accG[rt][ct][r] + bg, 0.f) + fmaxf(accR[rt][ct][r] + br, 0.f),
                        HoutF + (size_t)row * DIM + col);
                }
        }
    } else {
        // bf16: LDS transpose -> coalesced full-line nt writes
        __syncthreads();
        short* eOut = (short*)aggB;
        #pragma unroll
        for (int ct = 0; ct < 2; ++ct) {
            const int col = w * 32 + ct * 16 + lr;
            const float bg = bgc[col];
            const float br = bres[col];
            #pragma unroll
            for (int rt = 0; rt < 2; ++rt)
                #pragma unroll
                for (int r = 0; r < 4; ++r) {
                    const int row = rt * 16 + lk * 4 + r;
                    eOut[row * DIM + col] = (short)f2b(
                        fmaxf(accG[rt][ct][r] + bg, 0.f) + fmaxf(accR[rt][ct][r] + br, 0.f));
                }
        }
        __syncthreads();
        #pragma unroll
        for (int i = 0; i < 2; ++i) {
            const int id = tid + i * 256;
            const int row = id >> 4;
            const int col8 = (id & 15) * 8;
            __builtin_nontemporal_store(
                *reinterpret_cast<const u4v*>(eOut + row * DIM + col8),
                reinterpret_cast<u4v*>(HoutB + (size_t)(rowBase + row) * DIM + col8));
        }
    }
}

// ================================================================ fp32 fallback path
__global__ void init_mm(const float* __restrict__ X, const float* __restrict__ W,
                        float* __restrict__ H) {
    __shared__ float sF[8 * IN_FEATS];
    const int tid = threadIdx.x;
    const long rowBase = (long)blockIdx.x * 8;
    for (int i = tid; i < 8 * IN_FEATS; i += 256)
        sF[i] = X[rowBase * IN_FEATS + i];
    __syncthreads();
    const int r = tid >> 5;
    const int c = (tid & 31) * 4;
    float4 acc = make_float4(0.f, 0.f, 0.f, 0.f);
    for (int k = 0; k < IN_FEATS; ++k) {
        const float a = sF[r * IN_FEATS + k];
        const float4 w = *reinterpret_cast<const float4*>(W + k * DIM + c);
        acc.x += a * w.x; acc.y += a * w.y; acc.z += a * w.z; acc.w += a * w.w;
    }
    *reinterpret_cast<float4*>(H + (rowBase + r) * DIM + c) = acc;
}

__global__ void zero_f4(float4* __restrict__ p, int n4) {
    int i = blockIdx.x * blockDim.x + threadIdx.x;
    if (i < n4) p[i] = make_float4(0.f, 0.f, 0.f, 0.f);
}

__global__ void scatter_add(const float* __restrict__ H, const int* __restrict__ src,
                            const int* __restrict__ dst, float* __restrict__ agg) {
    const long t = (long)blockIdx.x * blockDim.x + threadIdx.x;
    const int e = (int)(t >> 5);
    const int lane = (int)(t & 31);
    if (e >= N_EDGES) return;
    const int s = src[e];
    const int d = dst[e];
    const float4 v = *reinterpret_cast<const float4*>(H + (long)s * DIM + lane * 4);
    float* o = agg + (long)d * DIM + lane * 4;
    unsafeAtomicAdd(o + 0, v.x);
    unsafeAtomicAdd(o + 1, v.y);
    unsafeAtomicAdd(o + 2, v.z);
    unsafeAtomicAdd(o + 3, v.w);
}

__global__ void layer_mm(const float* __restrict__ agg, float* __restrict__ H,
                         const float* __restrict__ Wgc, const float* __restrict__ bgc,
                         const float* __restrict__ Wres, const float* __restrict__ bres) {
    __shared__ float sA[8][DIM];
    __shared__ float sH[8][DIM];
    const int tid = threadIdx.x;
    const long rowBase = (long)blockIdx.x * 8;
    const int r = tid >> 5;
    const int c = (tid & 31) * 4;
    *reinterpret_cast<float4*>(&sA[r][c]) =
        *reinterpret_cast<const float4*>(agg + (rowBase + r) * DIM + c);
    *reinterpret_cast<float4*>(&sH[r][c]) =
        *reinterpret_cast<const float4*>(H + (rowBase + r) * DIM + c);
    __syncthreads();
    float4 a1 = make_float4(0.f, 0.f, 0.f, 0.f);
    float4 a2 = make_float4(0.f, 0.f, 0.f, 0.f);
    #pragma unroll 8
    for (int k = 0; k < DIM; ++k) {
        const float av = sA[r][k];
        const float hv = sH[r][k];
        const float4 wg = *reinterpret_cast<const float4*>(Wgc + k * DIM + c);
        const float4 wr = *reinterpret_cast<const float4*>(Wres + k * DIM + c);
        a1.x += av * wg.x; a1.y += av * wg.y; a1.z += av * wg.z; a1.w += av * wg.w;
        a2.x += hv * wr.x; a2.y += hv * wr.y; a2.z += hv * wr.z; a2.w += hv * wr.w;
    }
    const float4 bg = *reinterpret_cast<const float4*>(bgc + c);
    const float4 br = *reinterpret_cast<const float4*>(bres + c);
    float4 o;
    o.x = fmaxf(a1.x + bg.x, 0.f) + fmaxf(a2.x + br.x, 0.f);
    o.y = fmaxf(a1.y + bg.y, 0.f) + fmaxf(a2.y + br.y, 0.f);
    o.z = fmaxf(a1.z + bg.z, 0.f) + fmaxf(a2.z + br.z, 0.f);
    o.w = fmaxf(a1.w + bg.w, 0.f) + fmaxf(a2.w + br.w, 0.f);
    *reinterpret_cast<float4*>(H + (rowBase + r) * DIM + c) = o;
}

// ================================================================ launch
extern "C" void kernel_launch(void* const* d_in, const int* in_sizes, int n_in,
                              void* d_out, int out_size, void* d_ws, size_t ws_size,
                              hipStream_t stream) {
    const float* node_feats = (const float*)d_in[0];
    const int*   src        = (const int*)d_in[1];
    const int*   dst        = (const int*)d_in[2];
    const float* W_init     = (const float*)d_in[3];
    const float* W_gc       = (const float*)d_in[4];
    const float* b_gc       = (const float*)d_in[5];
    const float* W_res      = (const float*)d_in[6];
    const float* b_res      = (const float*)d_in[7];

    const size_t HB_BYTES  = (size_t)N_NODES * DIM * sizeof(unsigned short);
    const size_t RP_BYTES  = ((size_t)(N_NODES + 1) * 4 + 255) & ~255ull;
    const size_t DEG_BYTES = ((size_t)N_NODES * 4 + 255) & ~255ull;
    const size_t CUR_BYTES = DEG_BYTES;
    const size_t BS_BYTES  = (((size_t)(N_NODES / 256)) * 4 + 255) & ~255ull;
    const size_t EIDX_BYTES = (size_t)N_EDGES * 4;
    const size_t NEED = 2 * HB_BYTES + RP_BYTES + DEG_BYTES + CUR_BYTES + BS_BYTES + EIDX_BYTES;

    if (ws_size >= NEED) {
        char* w = (char*)d_ws;
        unsigned short* Ha = (unsigned short*)w;      w += HB_BYTES;
        unsigned short* Hb = (unsigned short*)w;      w += HB_BYTES;
        int* rowptr = (int*)w;                        w += RP_BYTES;
        int* small  = (int*)w;                        w += DEG_BYTES;
        int* wtarea = (int*)w;                        w += CUR_BYTES;
        w += BS_BYTES;
        int* eidx   = (int*)w;

        int* ccnt       = small;
        int* bcur       = small + NCHUNK;
        int* bucketBase = small + 2 * NCHUNK;
        unsigned int* bedge = (unsigned int*)Hb;
        unsigned short* Wt  = (unsigned short*)wtarea;
        unsigned short* WtI = Wt + 6 * 16384;
        float* Hout = (float*)d_out;

        zero_i<<<1, 256, 0, stream>>>(small, 2 * NCHUNK);
        coarse_hist<<<EBLKS, 256, 0, stream>>>(dst, ccnt);
        coarse_scan<<<1, NCHUNK, 0, stream>>>(ccnt, bucketBase);
        bucket_pass<<<EBLKS, 256, 0, stream>>>(src, dst, bucketBase, bcur, bedge);
        csr_pass<<<NCHUNK, 512, 0, stream>>>(bedge, bucketBase, rowptr, eidx);

        wcvt<<<6 * 64, 256, 0, stream>>>(W_gc, W_res, Wt);
        wcvt_init<<<(128 * KUSE + 255) / 256, 256, 0, stream>>>(W_init, WtI);
        init_mfma<<<N_NODES / 32, 256, 0, stream>>>(node_feats, WtI, Ha);

        layer_mfma<0><<<N_NODES / 32, 256, 0, stream>>>(
            Ha, Hb, nullptr, rowptr, eidx, Wt + 0 * 16384, Wt + 3 * 16384, b_gc, b_res);
        layer_mfma<0><<<N_NODES / 32, 256, 0, stream>>>(
            Hb, Ha, nullptr, rowptr, eidx, Wt + 1 * 16384, Wt + 4 * 16384,
            b_gc + DIM, b_res + DIM);
        layer_mfma<1><<<N_NODES / 32, 256, 0, stream>>>(
            Ha, nullptr, Hout, rowptr, eidx, Wt + 2 * 16384, Wt + 5 * 16384,
            b_gc + 2 * DIM, b_res + 2 * DIM);
    } else {
        float* H   = (float*)d_out;
        float* agg = (float*)d_ws;
        const int n4 = N_NODES * DIM / 4;
        init_mm<<<N_NODES / 8, 256, 0, stream>>>(node_feats, W_init, H);
        for (int l = 0; l < N_LAYERS; ++l) {
            zero_f4<<<(n4 + 255) / 256, 256, 0, stream>>>((float4*)agg, n4);
            scatter_add<<<(N_EDGES * 32) / 256, 256, 0, stream>>>(H, src, dst, agg);
            layer_mm<<<N_NODES / 8, 256, 0, stream>>>(agg, H,
                W_gc + (size_t)l * DIM * DIM, b_gc + (size_t)l * DIM,
                W_res + (size_t)l * DIM * DIM, b_res + (size_t)l * DIM);
        }
    }
}

// Round 10
// 597.495 us; speedup vs baseline: 1.0204x; 1.0204x over previous
//
#include <hip/hip_runtime.h>

#define N_NODES 296960
#define N_EDGES 2375680
#define IN_FEATS 75
#define DIM 128
#define N_LAYERS 3
#define ECAP 4096                        // staged edge indices (16 KB, aliases both tiles)
#define KPAD 104                         // init LDS row stride (shorts)
#define KUSE 96                          // init K padded to 3x32
#define NCHUNK 128                       // CSR super-chunks
#define CHN (N_NODES / NCHUNK)           // 2320 nodes per chunk
#define ETILE 2048                       // edges per bucketing block
#define EBLKS (N_EDGES / ETILE)          // 1160
#define CVPT 5                           // scan values/thread: 512*5 = 2560 >= 2320

static_assert(N_NODES % 256 == 0, "node count divisible by 256");
static_assert(N_EDGES % ETILE == 0, "edge count divisible by tile");
static_assert(NCHUNK * CHN == N_NODES, "chunks cover nodes exactly");

typedef __attribute__((ext_vector_type(8))) short s8v;   // 8 bf16 = 4 VGPR MFMA frag
typedef __attribute__((ext_vector_type(4))) float f4v;   // 4 f32 accum frag

__device__ __forceinline__ float u2f(unsigned int x) {
    union { unsigned int u; float f; } v; v.u = x; return v.f;
}
__device__ __forceinline__ unsigned short f2b(float f) {   // f32 -> bf16 RNE
    union { float f; unsigned int u; } v; v.f = f;
    unsigned int r = v.u + 0x7fffu + ((v.u >> 16) & 1u);
    return (unsigned short)(r >> 16);
}
__device__ __forceinline__ void addbf8(f4v& a, f4v& b, uint4 q) {  // 8 bf16 -> f32 accum
    a.x += u2f(q.x << 16); a.y += u2f(q.x & 0xffff0000u);
    a.z += u2f(q.y << 16); a.w += u2f(q.y & 0xffff0000u);
    b.x += u2f(q.z << 16); b.y += u2f(q.z & 0xffff0000u);
    b.z += u2f(q.w << 16); b.w += u2f(q.w & 0xffff0000u);
}

// ================================================================ CSR build (locality-aware 2-pass sort)
__global__ void zero_i(int* __restrict__ p, int n) {
    int i = blockIdx.x * blockDim.x + threadIdx.x;
    if (i < n) p[i] = 0;
}

__global__ __launch_bounds__(256) void coarse_hist(const int* __restrict__ dst,
                                                   int* __restrict__ ccnt) {
    __shared__ int cnt[NCHUNK];
    const int tid = threadIdx.x;
    if (tid < NCHUNK) cnt[tid] = 0;
    __syncthreads();
    const int base = blockIdx.x * ETILE;
    #pragma unroll
    for (int i = 0; i < ETILE / 256; ++i) {
        const int d = dst[base + i * 256 + tid];
        atomicAdd(&cnt[d / CHN], 1);
    }
    __syncthreads();
    if (tid < NCHUNK && cnt[tid] > 0) atomicAdd(&ccnt[tid], cnt[tid]);
}

__global__ void coarse_scan(const int* __restrict__ ccnt, int* __restrict__ bucketBase) {
    __shared__ int lds[NCHUNK];
    const int tid = threadIdx.x;
    if (tid < NCHUNK) lds[tid] = ccnt[tid];
    __syncthreads();
    if (tid == 0) {
        int run = 0;
        for (int k = 0; k < NCHUNK; ++k) {
            const int v = lds[k];
            lds[k] = run;
            run += v;
        }
        bucketBase[NCHUNK] = run;
    }
    __syncthreads();
    if (tid < NCHUNK) bucketBase[tid] = lds[tid];
}

__global__ __launch_bounds__(256) void bucket_pass(
    const int* __restrict__ src, const int* __restrict__ dst,
    const int* __restrict__ bucketBase, int* __restrict__ bcur,
    unsigned int* __restrict__ bedge) {
    __shared__ int cnt[NCHUNK];
    __shared__ int cnt2[NCHUNK];
    __shared__ int basei[NCHUNK];
    const int tid = threadIdx.x;
    if (tid < NCHUNK) { cnt[tid] = 0; cnt2[tid] = 0; }
    __syncthreads();

    const int base = blockIdx.x * ETILE;
    int s8[ETILE / 256], b8[ETILE / 256], dl8[ETILE / 256];
    #pragma unroll
    for (int i = 0; i < ETILE / 256; ++i) {
        const int e = base + i * 256 + tid;
        s8[i] = src[e];
        const int d = dst[e];
        b8[i] = d / CHN;
        dl8[i] = d - b8[i] * CHN;
        atomicAdd(&cnt[b8[i]], 1);
    }
    __syncthreads();
    if (tid < NCHUNK && cnt[tid] > 0)
        basei[tid] = bucketBase[tid] + atomicAdd(&bcur[tid], cnt[tid]);
    __syncthreads();
    #pragma unroll
    for (int i = 0; i < ETILE / 256; ++i) {
        const int pos = basei[b8[i]] + atomicAdd(&cnt2[b8[i]], 1);
        bedge[pos] = ((unsigned int)dl8[i] << 19) | (unsigned int)s8[i];
    }
}

__global__ __launch_bounds__(512) void csr_pass(
    const unsigned int* __restrict__ bedge, const int* __restrict__ bucketBase,
    int* __restrict__ rowptr, int* __restrict__ eidx) {
    __shared__ int cnt[512 * CVPT];
    __shared__ int wexcl[9];
    const int tid = threadIdx.x;
    const int c = blockIdx.x;
    const int nodeBase = c * CHN;
    const int segBeg = bucketBase[c];
    const int nseg = bucketBase[c + 1] - segBeg;

    #pragma unroll
    for (int j = 0; j < CVPT; ++j) cnt[tid * CVPT + j] = 0;
    __syncthreads();

    for (int i = tid; i < nseg; i += 512)
        atomicAdd(&cnt[bedge[segBeg + i] >> 19], 1);
    __syncthreads();

    int v[CVPT];
    int s = 0;
    #pragma unroll
    for (int j = 0; j < CVPT; ++j) { v[j] = cnt[tid * CVPT + j]; s += v[j]; }
    const int lane = tid & 63, wid = tid >> 6;
    int x = s;
    #pragma unroll
    for (int st = 1; st < 64; st <<= 1) {
        const int t = __shfl_up(x, st, 64);
        if (lane >= st) x += t;
    }
    if (lane == 63) wexcl[wid + 1] = x;
    __syncthreads();
    if (tid == 0) {
        wexcl[0] = 0;
        for (int k = 1; k <= 8; ++k) wexcl[k] += wexcl[k - 1];
    }
    __syncthreads();
    int run = segBeg + wexcl[wid] + (x - s);
    #pragma unroll
    for (int j = 0; j < CVPT; ++j) { cnt[tid * CVPT + j] = run; run += v[j]; }
    __syncthreads();

    for (int n = tid; n < CHN; n += 512)
        rowptr[nodeBase + n] = cnt[n];
    if (c == NCHUNK - 1 && tid == 0) rowptr[N_NODES] = N_EDGES;
    __syncthreads();

    for (int i = tid; i < nseg; i += 512) {
        const unsigned int p = bedge[segBeg + i];
        const int pos = atomicAdd(&cnt[p >> 19], 1);
        eidx[pos] = (int)(p & 0x7FFFFu);
    }
}

// ================================================================ weight transpose+cvt (layer + init merged)
// blocks 0..383: layer mats Wt[m][n][k]=bf16(W_m[k][n]); blocks 384..431: WtI[n][k] padded
__global__ void wcvt_all(const float* __restrict__ Wgc, const float* __restrict__ Wres,
                         const float* __restrict__ Wi,
                         unsigned short* __restrict__ Wt, unsigned short* __restrict__ WtI) {
    if (blockIdx.x < 384) {
        const int m = blockIdx.x >> 6;
        const int idx = (blockIdx.x & 63) * 256 + threadIdx.x;
        const float* src = (m < 3) ? (Wgc + m * 16384) : (Wres + (m - 3) * 16384);
        const int n = idx >> 7, k = idx & 127;
        Wt[m * 16384 + idx] = f2b(src[k * 128 + n]);
    } else {
        const int idx = (blockIdx.x - 384) * 256 + threadIdx.x;
        if (idx < 128 * KUSE) {
            const int n = idx / KUSE, k = idx - n * KUSE;
            WtI[idx] = (k < IN_FEATS) ? f2b(Wi[(size_t)k * DIM + n]) : (unsigned short)0;
        }
    }
}

// ================================================================ h0 = X @ W_init via MFMA -> bf16 (LDS transpose epilogue)
__global__ __launch_bounds__(256) void init_mfma(const float* __restrict__ X,
                                                 const unsigned short* __restrict__ WtI,
                                                 unsigned short* __restrict__ H) {
    __shared__ short sX[32][KPAD];
    __shared__ short sOut[32][DIM];
    const int tid = threadIdx.x;
    const int rowBase = blockIdx.x * 32;

    for (int idx = tid; idx < 32 * IN_FEATS; idx += 256) {
        const int row = idx / IN_FEATS;
        const int k = idx - row * IN_FEATS;
        sX[row][k] = (short)f2b(X[(size_t)rowBase * IN_FEATS + idx]);
    }
    #pragma unroll
    for (int i = 0; i < 4; ++i) {
        const int idx = tid + i * 256;
        const int row = idx >> 5;
        const int col = IN_FEATS + (idx & 31);
        if (col < KPAD) sX[row][col] = 0;
    }
    __syncthreads();

    const int w = tid >> 6;
    const int l = tid & 63;
    const int lr = l & 15;
    const int lk = l >> 4;

    f4v acc[2][2] = {{{0.f,0.f,0.f,0.f},{0.f,0.f,0.f,0.f}},{{0.f,0.f,0.f,0.f},{0.f,0.f,0.f,0.f}}};

    #pragma unroll
    for (int kb = 0; kb < 3; ++kb) {
        const int kofs = kb * 32 + lk * 8;
        s8v a[2], b[2];
        a[0] = *reinterpret_cast<const s8v*>(&sX[lr][kofs]);
        a[1] = *reinterpret_cast<const s8v*>(&sX[16 + lr][kofs]);
        #pragma unroll
        for (int ct = 0; ct < 2; ++ct) {
            const int col = w * 32 + ct * 16 + lr;
            b[ct] = *reinterpret_cast<const s8v*>(WtI + (size_t)col * KUSE + kofs);
        }
        #pragma unroll
        for (int rt = 0; rt < 2; ++rt)
            #pragma unroll
            for (int ct = 0; ct < 2; ++ct)
                acc[rt][ct] = __builtin_amdgcn_mfma_f32_16x16x32_bf16(a[rt], b[ct], acc[rt][ct], 0, 0, 0);
    }

    #pragma unroll
    for (int ct = 0; ct < 2; ++ct) {
        const int col = w * 32 + ct * 16 + lr;
        #pragma unroll
        for (int rt = 0; rt < 2; ++rt)
            #pragma unroll
            for (int r = 0; r < 4; ++r) {
                const int row = rt * 16 + lk * 4 + r;
                sOut[row][col] = (short)f2b(acc[rt][ct][r]);
            }
    }
    __syncthreads();
    #pragma unroll
    for (int i = 0; i < 2; ++i) {
        const int id = tid + i * 256;
        const int row = id >> 4;
        const int col8 = (id & 15) * 8;
        *reinterpret_cast<uint4*>(H + (size_t)(rowBase + row) * DIM + col8) =
            *reinterpret_cast<const uint4*>(&sOut[row][col8]);
    }
}

// ================================================================ fused gather + dual MFMA GEMM
// gather: 16 groups of 16 lanes, 2 nodes/group, uint4 row-loads, 4-deep
// epilogue (bf16): LDS transpose -> coalesced 16B/lane full-line writes
template <int LAST>
__global__ __launch_bounds__(256) void layer_mfma(
    const unsigned short* __restrict__ Hin, unsigned short* __restrict__ HoutB,
    float* __restrict__ HoutF,
    const int* __restrict__ rowptr, const int* __restrict__ eidx,
    const unsigned short* __restrict__ WgcT, const unsigned short* __restrict__ WresT,
    const float* __restrict__ bgc, const float* __restrict__ bres) {
    __shared__ short sTiles[2][32][DIM];     // [0]=agg, [1]=own : 16 KB
    int* sE = (int*)&sTiles[0][0][0];        // aliases both tiles during staging
    char* aggB = (char*)&sTiles[0][0][0];
    char* ownB = (char*)&sTiles[1][0][0];

    const int tid = threadIdx.x;
    const int rowBase = blockIdx.x * 32;

    const int blkBeg = rowptr[rowBase];
    const int blkEnd = rowptr[rowBase + 32];
    const int nE = blkEnd - blkBeg;
    const int nStage = (nE < ECAP) ? nE : ECAP;

    for (int i = tid; i < nStage; i += 256)
        sE[i] = eidx[blkBeg + i];
    __syncthreads();

    // ---- gather ----
    const int gg = tid >> 4;
    const int lane16 = tid & 15;
    const unsigned short* HinL = Hin + lane16 * 8;

    int begv[2], endv[2], rel[2];
    f4v accA[2], accB[2];
    uint4 own[2];
    int md = 0;
    #pragma unroll
    for (int ii = 0; ii < 2; ++ii) {
        const int node = rowBase + gg * 2 + ii;
        begv[ii] = rowptr[node];
        endv[ii] = rowptr[node + 1];
        rel[ii] = begv[ii] - blkBeg;
        own[ii] = *reinterpret_cast<const uint4*>(HinL + (size_t)node * DIM);
        accA[ii] = (f4v){0.f, 0.f, 0.f, 0.f};
        accB[ii] = (f4v){0.f, 0.f, 0.f, 0.f};
        const int d = endv[ii] - begv[ii];
        md = (d > md) ? d : md;
    }

    if (nE <= ECAP) {
        for (int t = 0; t < md; t += 4) {
            uint4 q[2][4];
            #pragma unroll
            for (int ii = 0; ii < 2; ++ii)
                #pragma unroll
                for (int j = 0; j < 4; ++j) {
                    q[ii][j] = make_uint4(0u, 0u, 0u, 0u);
                    const int e = begv[ii] + t + j;
                    if (e < endv[ii])
                        q[ii][j] = *reinterpret_cast<const uint4*>(
                            HinL + (size_t)sE[rel[ii] + t + j] * DIM);
                }
            #pragma unroll
            for (int ii = 0; ii < 2; ++ii)
                #pragma unroll
                for (int j = 0; j < 4; ++j)
                    addbf8(accA[ii], accB[ii], q[ii][j]);
        }
    } else {
        #pragma unroll
        for (int ii = 0; ii < 2; ++ii)
            for (int e = begv[ii]; e < endv[ii]; ++e)
                addbf8(accA[ii], accB[ii],
                       *reinterpret_cast<const uint4*>(HinL + (size_t)eidx[e] * DIM));
    }
    __syncthreads();   // sE dead

    // ---- write swizzled bf16 A-tiles: byte = row*256 + (kbyte ^ ((row&7)<<4)) ----
    #pragma unroll
    for (int ii = 0; ii < 2; ++ii) {
        const int row = gg * 2 + ii;
        const int kbyte = lane16 * 16;
        const int sw = kbyte ^ ((row & 7) << 4);
        uint4 p;
        p.x = (unsigned)f2b(accA[ii].x) | ((unsigned)f2b(accA[ii].y) << 16);
        p.y = (unsigned)f2b(accA[ii].z) | ((unsigned)f2b(accA[ii].w) << 16);
        p.z = (unsigned)f2b(accB[ii].x) | ((unsigned)f2b(accB[ii].y) << 16);
        p.w = (unsigned)f2b(accB[ii].z) | ((unsigned)f2b(accB[ii].w) << 16);
        *reinterpret_cast<uint4*>(aggB + row * 256 + sw) = p;
        *reinterpret_cast<uint4*>(ownB + row * 256 + sw) = own[ii];
    }
    __syncthreads();

    // ---- dual MFMA GEMM: wave w -> cols [w*32, w*32+32) ----
    const int w = tid >> 6;
    const int l = tid & 63;
    const int lr = l & 15;
    const int lk = l >> 4;

    f4v accG[2][2] = {{{0.f,0.f,0.f,0.f},{0.f,0.f,0.f,0.f}},{{0.f,0.f,0.f,0.f},{0.f,0.f,0.f,0.f}}};
    f4v accR[2][2] = {{{0.f,0.f,0.f,0.f},{0.f,0.f,0.f,0.f}},{{0.f,0.f,0.f,0.f},{0.f,0.f,0.f,0.f}}};

    #pragma unroll
    for (int kb = 0; kb < 4; ++kb) {
        const int kofs = kb * 32 + lk * 8;
        const int kbyte = kofs * 2;
        s8v aG[2], aO[2];
        #pragma unroll
        for (int rt = 0; rt < 2; ++rt) {
            const int row = rt * 16 + lr;
            const int byte = row * 256 + (kbyte ^ ((row & 7) << 4));
            aG[rt] = *reinterpret_cast<const s8v*>(aggB + byte);
            aO[rt] = *reinterpret_cast<const s8v*>(ownB + byte);
        }
        s8v bG[2], bR[2];
        #pragma unroll
        for (int ct = 0; ct < 2; ++ct) {
            const int col = w * 32 + ct * 16 + lr;
            const size_t off = (size_t)col * DIM + kofs;
            bG[ct] = *reinterpret_cast<const s8v*>(WgcT + off);
            bR[ct] = *reinterpret_cast<const s8v*>(WresT + off);
        }
        #pragma unroll
        for (int rt = 0; rt < 2; ++rt) {
            #pragma unroll
            for (int ct = 0; ct < 2; ++ct) {
                accG[rt][ct] = __builtin_amdgcn_mfma_f32_16x16x32_bf16(aG[rt], bG[ct], accG[rt][ct], 0, 0, 0);
                accR[rt][ct] = __builtin_amdgcn_mfma_f32_16x16x32_bf16(aO[rt], bR[ct], accR[rt][ct], 0, 0, 0);
            }
        }
    }

    if (LAST) {
        // f32 direct: 16 consecutive lanes x 4B = full 64B lines
        #pragma unroll
        for (int ct = 0; ct < 2; ++ct) {
            const int col = w * 32 + ct * 16 + lr;
            const float bg = bgc[col];
            const float br = bres[col];
            #pragma unroll
            for (int rt = 0; rt < 2; ++rt)
                #pragma unroll
                for (int r = 0; r < 4; ++r) {
                    const int row = rowBase + rt * 16 + lk * 4 + r;
                    HoutF[(size_t)row * DIM + col] =
                        fmaxf(accG[rt][ct][r] + bg, 0.f) + fmaxf(accR[rt][ct][r] + br, 0.f);
                }
        }
    } else {
        // bf16: LDS transpose -> coalesced full-line writes
        __syncthreads();
        short* eOut = (short*)aggB;
        #pragma unroll
        for (int ct = 0; ct < 2; ++ct) {
            const int col = w * 32 + ct * 16 + lr;
            const float bg = bgc[col];
            const float br = bres[col];
            #pragma unroll
            for (int rt = 0; rt < 2; ++rt)
                #pragma unroll
                for (int r = 0; r < 4; ++r) {
                    const int row = rt * 16 + lk * 4 + r;
                    eOut[row * DIM + col] = (short)f2b(
                        fmaxf(accG[rt][ct][r] + bg, 0.f) + fmaxf(accR[rt][ct][r] + br, 0.f));
                }
        }
        __syncthreads();
        #pragma unroll
        for (int i = 0; i < 2; ++i) {
            const int id = tid + i * 256;
            const int row = id >> 4;
            const int col8 = (id & 15) * 8;
            *reinterpret_cast<uint4*>(HoutB + (size_t)(rowBase + row) * DIM + col8) =
                *reinterpret_cast<const uint4*>(eOut + row * DIM + col8);
        }
    }
}

// ================================================================ fp32 fallback path
__global__ void init_mm(const float* __restrict__ X, const float* __restrict__ W,
                        float* __restrict__ H) {
    __shared__ float sF[8 * IN_FEATS];
    const int tid = threadIdx.x;
    const long rowBase = (long)blockIdx.x * 8;
    for (int i = tid; i < 8 * IN_FEATS; i += 256)
        sF[i] = X[rowBase * IN_FEATS + i];
    __syncthreads();
    const int r = tid >> 5;
    const int c = (tid & 31) * 4;
    float4 acc = make_float4(0.f, 0.f, 0.f, 0.f);
    for (int k = 0; k < IN_FEATS; ++k) {
        const float a = sF[r * IN_FEATS + k];
        const float4 w = *reinterpret_cast<const float4*>(W + k * DIM + c);
        acc.x += a * w.x; acc.y += a * w.y; acc.z += a * w.z; acc.w += a * w.w;
    }
    *reinterpret_cast<float4*>(H + (rowBase + r) * DIM + c) = acc;
}

__global__ void zero_f4(float4* __restrict__ p, int n4) {
    int i = blockIdx.x * blockDim.x + threadIdx.x;
    if (i < n4) p[i] = make_float4(0.f, 0.f, 0.f, 0.f);
}

__global__ void scatter_add(const float* __restrict__ H, const int* __restrict__ src,
                            const int* __restrict__ dst, float* __restrict__ agg) {
    const long t = (long)blockIdx.x * blockDim.x + threadIdx.x;
    const int e = (int)(t >> 5);
    const int lane = (int)(t & 31);
    if (e >= N_EDGES) return;
    const int s = src[e];
    const int d = dst[e];
    const float4 v = *reinterpret_cast<const float4*>(H + (long)s * DIM + lane * 4);
    float* o = agg + (long)d * DIM + lane * 4;
    unsafeAtomicAdd(o + 0, v.x);
    unsafeAtomicAdd(o + 1, v.y);
    unsafeAtomicAdd(o + 2, v.z);
    unsafeAtomicAdd(o + 3, v.w);
}

__global__ void layer_mm(const float* __restrict__ agg, float* __restrict__ H,
                         const float* __restrict__ Wgc, const float* __restrict__ bgc,
                         const float* __restrict__ Wres, const float* __restrict__ bres) {
    __shared__ float sA[8][DIM];
    __shared__ float sH[8][DIM];
    const int tid = threadIdx.x;
    const long rowBase = (long)blockIdx.x * 8;
    const int r = tid >> 5;
    const int c = (tid & 31) * 4;
    *reinterpret_cast<float4*>(&sA[r][c]) =
        *reinterpret_cast<const float4*>(agg + (rowBase + r) * DIM + c);
    *reinterpret_cast<float4*>(&sH[r][c]) =
        *reinterpret_cast<const float4*>(H + (rowBase + r) * DIM + c);
    __syncthreads();
    float4 a1 = make_float4(0.f, 0.f, 0.f, 0.f);
    float4 a2 = make_float4(0.f, 0.f, 0.f, 0.f);
    #pragma unroll 8
    for (int k = 0; k < DIM; ++k) {
        const float av = sA[r][k];
        const float hv = sH[r][k];
        const float4 wg = *reinterpret_cast<const float4*>(Wgc + k * DIM + c);
        const float4 wr = *reinterpret_cast<const float4*>(Wres + k * DIM + c);
        a1.x += av * wg.x; a1.y += av * wg.y; a1.z += av * wg.z; a1.w += av * wg.w;
        a2.x += hv * wr.x; a2.y += hv * wr.y; a2.z += hv * wr.z; a2.w += hv * wr.w;
    }
    const float4 bg = *reinterpret_cast<const float4*>(bgc + c);
    const float4 br = *reinterpret_cast<const float4*>(bres + c);
    float4 o;
    o.x = fmaxf(a1.x + bg.x, 0.f) + fmaxf(a2.x + br.x, 0.f);
    o.y = fmaxf(a1.y + bg.y, 0.f) + fmaxf(a2.y + br.y, 0.f);
    o.z = fmaxf(a1.z + bg.z, 0.f) + fmaxf(a2.z + br.z, 0.f);
    o.w = fmaxf(a1.w + bg.w, 0.f) + fmaxf(a2.w + br.w, 0.f);
    *reinterpret_cast<float4*>(H + (rowBase + r) * DIM + c) = o;
}

// ================================================================ launch
extern "C" void kernel_launch(void* const* d_in, const int* in_sizes, int n_in,
                              void* d_out, int out_size, void* d_ws, size_t ws_size,
                              hipStream_t stream) {
    const float* node_feats = (const float*)d_in[0];
    const int*   src        = (const int*)d_in[1];
    const int*   dst        = (const int*)d_in[2];
    const float* W_init     = (const float*)d_in[3];
    const float* W_gc       = (const float*)d_in[4];
    const float* b_gc       = (const float*)d_in[5];
    const float* W_res      = (const float*)d_in[6];
    const float* b_res      = (const float*)d_in[7];

    const size_t HB_BYTES  = (size_t)N_NODES * DIM * sizeof(unsigned short);
    const size_t RP_BYTES  = ((size_t)(N_NODES + 1) * 4 + 255) & ~255ull;
    const size_t DEG_BYTES = ((size_t)N_NODES * 4 + 255) & ~255ull;
    const size_t CUR_BYTES = DEG_BYTES;
    const size_t BS_BYTES  = (((size_t)(N_NODES / 256)) * 4 + 255) & ~255ull;
    const size_t EIDX_BYTES = (size_t)N_EDGES * 4;
    const size_t NEED = 2 * HB_BYTES + RP_BYTES + DEG_BYTES + CUR_BYTES + BS_BYTES + EIDX_BYTES;

    if (ws_size >= NEED) {
        char* w = (char*)d_ws;
        unsigned short* Ha = (unsigned short*)w;      w += HB_BYTES;
        unsigned short* Hb = (unsigned short*)w;      w += HB_BYTES;
        int* rowptr = (int*)w;                        w += RP_BYTES;
        int* small  = (int*)w;                        w += DEG_BYTES;
        int* wtarea = (int*)w;                        w += CUR_BYTES;
        w += BS_BYTES;
        int* eidx   = (int*)w;

        int* ccnt       = small;
        int* bcur       = small + NCHUNK;
        int* bucketBase = small + 2 * NCHUNK;
        unsigned int* bedge = (unsigned int*)Hb;
        unsigned short* Wt  = (unsigned short*)wtarea;
        unsigned short* WtI = Wt + 6 * 16384;
        float* Hout = (float*)d_out;

        zero_i<<<1, 256, 0, stream>>>(small, 2 * NCHUNK);
        coarse_hist<<<EBLKS, 256, 0, stream>>>(dst, ccnt);
        coarse_scan<<<1, NCHUNK, 0, stream>>>(ccnt, bucketBase);
        bucket_pass<<<EBLKS, 256, 0, stream>>>(src, dst, bucketBase, bcur, bedge);
        csr_pass<<<NCHUNK, 512, 0, stream>>>(bedge, bucketBase, rowptr, eidx);

        wcvt_all<<<384 + (128 * KUSE + 255) / 256, 256, 0, stream>>>(W_gc, W_res, W_init, Wt, WtI);
        init_mfma<<<N_NODES / 32, 256, 0, stream>>>(node_feats, WtI, Ha);

        layer_mfma<0><<<N_NODES / 32, 256, 0, stream>>>(
            Ha, Hb, nullptr, rowptr, eidx, Wt + 0 * 16384, Wt + 3 * 16384, b_gc, b_res);
        layer_mfma<0><<<N_NODES / 32, 256, 0, stream>>>(
            Hb, Ha, nullptr, rowptr, eidx, Wt + 1 * 16384, Wt + 4 * 16384,
            b_gc + DIM, b_res + DIM);
        layer_mfma<1><<<N_NODES / 32, 256, 0, stream>>>(
            Ha, nullptr, Hout, rowptr, eidx, Wt + 2 * 16384, Wt + 5 * 16384,
            b_gc + 2 * DIM, b_res + 2 * DIM);
    } else {
        float* H   = (float*)d_out;
        float* agg = (float*)d_ws;
        const int n4 = N_NODES * DIM / 4;
        init_mm<<<N_NODES / 8, 256, 0, stream>>>(node_feats, W_init, H);
        for (int l = 0; l < N_LAYERS; ++l) {
            zero_f4<<<(n4 + 255) / 256, 256, 0, stream>>>((float4*)agg, n4);
            scatter_add<<<(N_EDGES * 32) / 256, 256, 0, stream>>>(H, src, dst, agg);
            layer_mm<<<N_NODES / 8, 256, 0, stream>>>(agg, H,
                W_gc + (size_t)l * DIM * DIM, b_gc + (size_t)l * DIM,
                W_res + (size_t)l * DIM * DIM, b_res + (size_t)l * DIM);
        }
    }
}

// Round 11
// 590.445 us; speedup vs baseline: 1.0326x; 1.0119x over previous
//
#include <hip/hip_runtime.h>

#define N_NODES 296960
#define N_EDGES 2375680
#define IN_FEATS 75
#define DIM 128
#define N_LAYERS 3
#define ECAP 4096                        // staged edge indices (16 KB, aliases both tiles)
#define KPAD 104                         // init LDS row stride (shorts)
#define KUSE 96                          // init K padded to 3x32
#define NCHUNK 256                       // CSR super-chunks (1 csr_pass block per CU)
#define CHN (N_NODES / NCHUNK)           // 1160 nodes per chunk (dstLow: 11 bits; src: 19 bits)
#define ETILE 2048                       // edges per bucketing block
#define EBLKS (N_EDGES / ETILE)          // 1160
#define CVPT 3                           // scan values/thread: 512*3 = 1536 >= 1160

static_assert(N_NODES % 256 == 0, "node count divisible by 256");
static_assert(N_EDGES % ETILE == 0, "edge count divisible by tile");
static_assert(NCHUNK * CHN == N_NODES, "chunks cover nodes exactly");
static_assert(CHN < 2048, "dstLow must fit 11 bits");
static_assert(512 * CVPT >= CHN, "scan covers chunk");

typedef __attribute__((ext_vector_type(8))) short s8v;   // 8 bf16 = 4 VGPR MFMA frag
typedef __attribute__((ext_vector_type(4))) float f4v;   // 4 f32 accum frag

__device__ __forceinline__ float u2f(unsigned int x) {
    union { unsigned int u; float f; } v; v.u = x; return v.f;
}
__device__ __forceinline__ unsigned short f2b(float f) {   // f32 -> bf16 RNE
    union { float f; unsigned int u; } v; v.f = f;
    unsigned int r = v.u + 0x7fffu + ((v.u >> 16) & 1u);
    return (unsigned short)(r >> 16);
}
__device__ __forceinline__ void addbf8(f4v& a, f4v& b, uint4 q) {  // 8 bf16 -> f32 accum
    a.x += u2f(q.x << 16); a.y += u2f(q.x & 0xffff0000u);
    a.z += u2f(q.y << 16); a.w += u2f(q.y & 0xffff0000u);
    b.x += u2f(q.z << 16); b.y += u2f(q.z & 0xffff0000u);
    b.z += u2f(q.w << 16); b.w += u2f(q.w & 0xffff0000u);
}

// ================================================================ CSR build (locality-aware 2-pass sort)
__global__ void zero_i(int* __restrict__ p, int n) {
    int i = blockIdx.x * blockDim.x + threadIdx.x;
    if (i < n) p[i] = 0;
}

__global__ __launch_bounds__(256) void coarse_hist(const int* __restrict__ dst,
                                                   int* __restrict__ ccnt) {
    __shared__ int cnt[NCHUNK];
    const int tid = threadIdx.x;
    if (tid < NCHUNK) cnt[tid] = 0;
    __syncthreads();
    const int base = blockIdx.x * ETILE;
    #pragma unroll
    for (int i = 0; i < ETILE / 256; ++i) {
        const int d = dst[base + i * 256 + tid];
        atomicAdd(&cnt[d / CHN], 1);
    }
    __syncthreads();
    if (tid < NCHUNK && cnt[tid] > 0) atomicAdd(&ccnt[tid], cnt[tid]);
}

__global__ void coarse_scan(const int* __restrict__ ccnt, int* __restrict__ bucketBase) {
    __shared__ int lds[NCHUNK];
    const int tid = threadIdx.x;
    if (tid < NCHUNK) lds[tid] = ccnt[tid];
    __syncthreads();
    if (tid == 0) {
        int run = 0;
        for (int k = 0; k < NCHUNK; ++k) {
            const int v = lds[k];
            lds[k] = run;
            run += v;
        }
        bucketBase[NCHUNK] = run;
    }
    __syncthreads();
    if (tid < NCHUNK) bucketBase[tid] = lds[tid];
}

__global__ __launch_bounds__(256) void bucket_pass(
    const int* __restrict__ src, const int* __restrict__ dst,
    const int* __restrict__ bucketBase, int* __restrict__ bcur,
    unsigned int* __restrict__ bedge) {
    __shared__ int cnt[NCHUNK];
    __shared__ int cnt2[NCHUNK];
    __shared__ int basei[NCHUNK];
    const int tid = threadIdx.x;
    if (tid < NCHUNK) { cnt[tid] = 0; cnt2[tid] = 0; }
    __syncthreads();

    const int base = blockIdx.x * ETILE;
    int s8[ETILE / 256], b8[ETILE / 256], dl8[ETILE / 256];
    #pragma unroll
    for (int i = 0; i < ETILE / 256; ++i) {
        const int e = base + i * 256 + tid;
        s8[i] = src[e];
        const int d = dst[e];
        b8[i] = d / CHN;
        dl8[i] = d - b8[i] * CHN;
        atomicAdd(&cnt[b8[i]], 1);
    }
    __syncthreads();
    if (tid < NCHUNK && cnt[tid] > 0)
        basei[tid] = bucketBase[tid] + atomicAdd(&bcur[tid], cnt[tid]);
    __syncthreads();
    #pragma unroll
    for (int i = 0; i < ETILE / 256; ++i) {
        const int pos = basei[b8[i]] + atomicAdd(&cnt2[b8[i]], 1);
        bedge[pos] = ((unsigned int)dl8[i] << 19) | (unsigned int)s8[i];
    }
}

__global__ __launch_bounds__(512) void csr_pass(
    const unsigned int* __restrict__ bedge, const int* __restrict__ bucketBase,
    int* __restrict__ rowptr, int* __restrict__ eidx) {
    __shared__ int cnt[512 * CVPT];   // 1536 >= CHN
    __shared__ int wexcl[9];
    const int tid = threadIdx.x;
    const int c = blockIdx.x;
    const int nodeBase = c * CHN;
    const int segBeg = bucketBase[c];
    const int nseg = bucketBase[c + 1] - segBeg;

    #pragma unroll
    for (int j = 0; j < CVPT; ++j) cnt[tid * CVPT + j] = 0;
    __syncthreads();

    for (int i = tid; i < nseg; i += 512)
        atomicAdd(&cnt[bedge[segBeg + i] >> 19], 1);
    __syncthreads();

    int v[CVPT];
    int s = 0;
    #pragma unroll
    for (int j = 0; j < CVPT; ++j) { v[j] = cnt[tid * CVPT + j]; s += v[j]; }
    const int lane = tid & 63, wid = tid >> 6;
    int x = s;
    #pragma unroll
    for (int st = 1; st < 64; st <<= 1) {
        const int t = __shfl_up(x, st, 64);
        if (lane >= st) x += t;
    }
    if (lane == 63) wexcl[wid + 1] = x;
    __syncthreads();
    if (tid == 0) {
        wexcl[0] = 0;
        for (int k = 1; k <= 8; ++k) wexcl[k] += wexcl[k - 1];
    }
    __syncthreads();
    int run = segBeg + wexcl[wid] + (x - s);
    #pragma unroll
    for (int j = 0; j < CVPT; ++j) { cnt[tid * CVPT + j] = run; run += v[j]; }
    __syncthreads();

    for (int n = tid; n < CHN; n += 512)
        rowptr[nodeBase + n] = cnt[n];
    if (c == NCHUNK - 1 && tid == 0) rowptr[N_NODES] = N_EDGES;
    __syncthreads();

    for (int i = tid; i < nseg; i += 512) {
        const unsigned int p = bedge[segBeg + i];
        const int pos = atomicAdd(&cnt[p >> 19], 1);
        eidx[pos] = (int)(p & 0x7FFFFu);
    }
}

// ================================================================ weight transpose+cvt (layer + init merged)
__global__ void wcvt_all(const float* __restrict__ Wgc, const float* __restrict__ Wres,
                         const float* __restrict__ Wi,
                         unsigned short* __restrict__ Wt, unsigned short* __restrict__ WtI) {
    if (blockIdx.x < 384) {
        const int m = blockIdx.x >> 6;
        const int idx = (blockIdx.x & 63) * 256 + threadIdx.x;
        const float* src = (m < 3) ? (Wgc + m * 16384) : (Wres + (m - 3) * 16384);
        const int n = idx >> 7, k = idx & 127;
        Wt[m * 16384 + idx] = f2b(src[k * 128 + n]);
    } else {
        const int idx = (blockIdx.x - 384) * 256 + threadIdx.x;
        if (idx < 128 * KUSE) {
            const int n = idx / KUSE, k = idx - n * KUSE;
            WtI[idx] = (k < IN_FEATS) ? f2b(Wi[(size_t)k * DIM + n]) : (unsigned short)0;
        }
    }
}

// ================================================================ h0 = X @ W_init via MFMA -> bf16 (LDS transpose epilogue)
__global__ __launch_bounds__(256) void init_mfma(const float* __restrict__ X,
                                                 const unsigned short* __restrict__ WtI,
                                                 unsigned short* __restrict__ H) {
    __shared__ short sX[32][KPAD];
    __shared__ short sOut[32][DIM];
    const int tid = threadIdx.x;
    const int rowBase = blockIdx.x * 32;

    for (int idx = tid; idx < 32 * IN_FEATS; idx += 256) {
        const int row = idx / IN_FEATS;
        const int k = idx - row * IN_FEATS;
        sX[row][k] = (short)f2b(X[(size_t)rowBase * IN_FEATS + idx]);
    }
    #pragma unroll
    for (int i = 0; i < 4; ++i) {
        const int idx = tid + i * 256;
        const int row = idx >> 5;
        const int col = IN_FEATS + (idx & 31);
        if (col < KPAD) sX[row][col] = 0;
    }
    __syncthreads();

    const int w = tid >> 6;
    const int l = tid & 63;
    const int lr = l & 15;
    const int lk = l >> 4;

    f4v acc[2][2] = {{{0.f,0.f,0.f,0.f},{0.f,0.f,0.f,0.f}},{{0.f,0.f,0.f,0.f},{0.f,0.f,0.f,0.f}}};

    #pragma unroll
    for (int kb = 0; kb < 3; ++kb) {
        const int kofs = kb * 32 + lk * 8;
        s8v a[2], b[2];
        a[0] = *reinterpret_cast<const s8v*>(&sX[lr][kofs]);
        a[1] = *reinterpret_cast<const s8v*>(&sX[16 + lr][kofs]);
        #pragma unroll
        for (int ct = 0; ct < 2; ++ct) {
            const int col = w * 32 + ct * 16 + lr;
            b[ct] = *reinterpret_cast<const s8v*>(WtI + (size_t)col * KUSE + kofs);
        }
        #pragma unroll
        for (int rt = 0; rt < 2; ++rt)
            #pragma unroll
            for (int ct = 0; ct < 2; ++ct)
                acc[rt][ct] = __builtin_amdgcn_mfma_f32_16x16x32_bf16(a[rt], b[ct], acc[rt][ct], 0, 0, 0);
    }

    #pragma unroll
    for (int ct = 0; ct < 2; ++ct) {
        const int col = w * 32 + ct * 16 + lr;
        #pragma unroll
        for (int rt = 0; rt < 2; ++rt)
            #pragma unroll
            for (int r = 0; r < 4; ++r) {
                const int row = rt * 16 + lk * 4 + r;
                sOut[row][col] = (short)f2b(acc[rt][ct][r]);
            }
    }
    __syncthreads();
    #pragma unroll
    for (int i = 0; i < 2; ++i) {
        const int id = tid + i * 256;
        const int row = id >> 4;
        const int col8 = (id & 15) * 8;
        *reinterpret_cast<uint4*>(H + (size_t)(rowBase + row) * DIM + col8) =
            *reinterpret_cast<const uint4*>(&sOut[row][col8]);
    }
}

// ================================================================ fused gather + dual MFMA GEMM
template <int LAST>
__global__ __launch_bounds__(256) void layer_mfma(
    const unsigned short* __restrict__ Hin, unsigned short* __restrict__ HoutB,
    float* __restrict__ HoutF,
    const int* __restrict__ rowptr, const int* __restrict__ eidx,
    const unsigned short* __restrict__ WgcT, const unsigned short* __restrict__ WresT,
    const float* __restrict__ bgc, const float* __restrict__ bres) {
    __shared__ short sTiles[2][32][DIM];     // [0]=agg, [1]=own : 16 KB
    int* sE = (int*)&sTiles[0][0][0];        // aliases both tiles during staging
    char* aggB = (char*)&sTiles[0][0][0];
    char* ownB = (char*)&sTiles[1][0][0];

    const int tid = threadIdx.x;
    const int rowBase = blockIdx.x * 32;

    const int blkBeg = rowptr[rowBase];
    const int blkEnd = rowptr[rowBase + 32];
    const int nE = blkEnd - blkBeg;
    const int nStage = (nE < ECAP) ? nE : ECAP;

    for (int i = tid; i < nStage; i += 256)
        sE[i] = eidx[blkBeg + i];
    __syncthreads();

    // ---- gather: 16 groups of 16 lanes, 2 nodes/group, uint4 row-loads, 4-deep ----
    const int gg = tid >> 4;
    const int lane16 = tid & 15;
    const unsigned short* HinL = Hin + lane16 * 8;

    int begv[2], endv[2], rel[2];
    f4v accA[2], accB[2];
    uint4 own[2];
    int md = 0;
    #pragma unroll
    for (int ii = 0; ii < 2; ++ii) {
        const int node = rowBase + gg * 2 + ii;
        begv[ii] = rowptr[node];
        endv[ii] = rowptr[node + 1];
        rel[ii] = begv[ii] - blkBeg;
        own[ii] = *reinterpret_cast<const uint4*>(HinL + (size_t)node * DIM);
        accA[ii] = (f4v){0.f, 0.f, 0.f, 0.f};
        accB[ii] = (f4v){0.f, 0.f, 0.f, 0.f};
        const int d = endv[ii] - begv[ii];
        md = (d > md) ? d : md;
    }

    if (nE <= ECAP) {
        for (int t = 0; t < md; t += 4) {
            uint4 q[2][4];
            #pragma unroll
            for (int ii = 0; ii < 2; ++ii)
                #pragma unroll
                for (int j = 0; j < 4; ++j) {
                    q[ii][j] = make_uint4(0u, 0u, 0u, 0u);
                    const int e = begv[ii] + t + j;
                    if (e < endv[ii])
                        q[ii][j] = *reinterpret_cast<const uint4*>(
                            HinL + (size_t)sE[rel[ii] + t + j] * DIM);
                }
            #pragma unroll
            for (int ii = 0; ii < 2; ++ii)
                #pragma unroll
                for (int j = 0; j < 4; ++j)
                    addbf8(accA[ii], accB[ii], q[ii][j]);
        }
    } else {
        #pragma unroll
        for (int ii = 0; ii < 2; ++ii)
            for (int e = begv[ii]; e < endv[ii]; ++e)
                addbf8(accA[ii], accB[ii],
                       *reinterpret_cast<const uint4*>(HinL + (size_t)eidx[e] * DIM));
    }
    __syncthreads();   // sE dead

    // ---- write swizzled bf16 A-tiles: byte = row*256 + (kbyte ^ ((row&7)<<4)) ----
    #pragma unroll
    for (int ii = 0; ii < 2; ++ii) {
        const int row = gg * 2 + ii;
        const int kbyte = lane16 * 16;
        const int sw = kbyte ^ ((row & 7) << 4);
        uint4 p;
        p.x = (unsigned)f2b(accA[ii].x) | ((unsigned)f2b(accA[ii].y) << 16);
        p.y = (unsigned)f2b(accA[ii].z) | ((unsigned)f2b(accA[ii].w) << 16);
        p.z = (unsigned)f2b(accB[ii].x) | ((unsigned)f2b(accB[ii].y) << 16);
        p.w = (unsigned)f2b(accB[ii].z) | ((unsigned)f2b(accB[ii].w) << 16);
        *reinterpret_cast<uint4*>(aggB + row * 256 + sw) = p;
        *reinterpret_cast<uint4*>(ownB + row * 256 + sw) = own[ii];
    }
    __syncthreads();

    // ---- dual MFMA GEMM: wave w -> cols [w*32, w*32+32) ----
    const int w = tid >> 6;
    const int l = tid & 63;
    const int lr = l & 15;
    const int lk = l >> 4;

    f4v accG[2][2] = {{{0.f,0.f,0.f,0.f},{0.f,0.f,0.f,0.f}},{{0.f,0.f,0.f,0.f},{0.f,0.f,0.f,0.f}}};
    f4v accR[2][2] = {{{0.f,0.f,0.f,0.f},{0.f,0.f,0.f,0.f}},{{0.f,0.f,0.f,0.f},{0.f,0.f,0.f,0.f}}};

    #pragma unroll
    for (int kb = 0; kb < 4; ++kb) {
        const int kofs = kb * 32 + lk * 8;
        const int kbyte = kofs * 2;
        s8v aG[2], aO[2];
        #pragma unroll
        for (int rt = 0; rt < 2; ++rt) {
            const int row = rt * 16 + lr;
            const int byte = row * 256 + (kbyte ^ ((row & 7) << 4));
            aG[rt] = *reinterpret_cast<const s8v*>(aggB + byte);
            aO[rt] = *reinterpret_cast<const s8v*>(ownB + byte);
        }
        s8v bG[2], bR[2];
        #pragma unroll
        for (int ct = 0; ct < 2; ++ct) {
            const int col = w * 32 + ct * 16 + lr;
            const size_t off = (size_t)col * DIM + kofs;
            bG[ct] = *reinterpret_cast<const s8v*>(WgcT + off);
            bR[ct] = *reinterpret_cast<const s8v*>(WresT + off);
        }
        #pragma unroll
        for (int rt = 0; rt < 2; ++rt) {
            #pragma unroll
            for (int ct = 0; ct < 2; ++ct) {
                accG[rt][ct] = __builtin_amdgcn_mfma_f32_16x16x32_bf16(aG[rt], bG[ct], accG[rt][ct], 0, 0, 0);
                accR[rt][ct] = __builtin_amdgcn_mfma_f32_16x16x32_bf16(aO[rt], bR[ct], accR[rt][ct], 0, 0, 0);
            }
        }
    }

    if (LAST) {
        #pragma unroll
        for (int ct = 0; ct < 2; ++ct) {
            const int col = w * 32 + ct * 16 + lr;
            const float bg = bgc[col];
            const float br = bres[col];
            #pragma unroll
            for (int rt = 0; rt < 2; ++rt)
                #pragma unroll
                for (int r = 0; r < 4; ++r) {
                    const int row = rowBase + rt * 16 + lk * 4 + r;
                    HoutF[(size_t)row * DIM + col] =
                        fmaxf(accG[rt][ct][r] + bg, 0.f) + fmaxf(accR[rt][ct][r] + br, 0.f);
                }
        }
    } else {
        __syncthreads();
        short* eOut = (short*)aggB;
        #pragma unroll
        for (int ct = 0; ct < 2; ++ct) {
            const int col = w * 32 + ct * 16 + lr;
            const float bg = bgc[col];
            const float br = bres[col];
            #pragma unroll
            for (int rt = 0; rt < 2; ++rt)
                #pragma unroll
                for (int r = 0; r < 4; ++r) {
                    const int row = rt * 16 + lk * 4 + r;
                    eOut[row * DIM + col] = (short)f2b(
                        fmaxf(accG[rt][ct][r] + bg, 0.f) + fmaxf(accR[rt][ct][r] + br, 0.f));
                }
        }
        __syncthreads();
        #pragma unroll
        for (int i = 0; i < 2; ++i) {
            const int id = tid + i * 256;
            const int row = id >> 4;
            const int col8 = (id & 15) * 8;
            *reinterpret_cast<uint4*>(HoutB + (size_t)(rowBase + row) * DIM + col8) =
                *reinterpret_cast<const uint4*>(eOut + row * DIM + col8);
        }
    }
}

// ================================================================ fp32 fallback path
__global__ void init_mm(const float* __restrict__ X, const float* __restrict__ W,
                        float* __restrict__ H) {
    __shared__ float sF[8 * IN_FEATS];
    const int tid = threadIdx.x;
    const long rowBase = (long)blockIdx.x * 8;
    for (int i = tid; i < 8 * IN_FEATS; i += 256)
        sF[i] = X[rowBase * IN_FEATS + i];
    __syncthreads();
    const int r = tid >> 5;
    const int c = (tid & 31) * 4;
    float4 acc = make_float4(0.f, 0.f, 0.f, 0.f);
    for (int k = 0; k < IN_FEATS; ++k) {
        const float a = sF[r * IN_FEATS + k];
        const float4 w = *reinterpret_cast<const float4*>(W + k * DIM + c);
        acc.x += a * w.x; acc.y += a * w.y; acc.z += a * w.z; acc.w += a * w.w;
    }
    *reinterpret_cast<float4*>(H + (rowBase + r) * DIM + c) = acc;
}

__global__ void zero_f4(float4* __restrict__ p, int n4) {
    int i = blockIdx.x * blockDim.x + threadIdx.x;
    if (i < n4) p[i] = make_float4(0.f, 0.f, 0.f, 0.f);
}

__global__ void scatter_add(const float* __restrict__ H, const int* __restrict__ src,
                            const int* __restrict__ dst, float* __restrict__ agg) {
    const long t = (long)blockIdx.x * blockDim.x + threadIdx.x;
    const int e = (int)(t >> 5);
    const int lane = (int)(t & 31);
    if (e >= N_EDGES) return;
    const int s = src[e];
    const int d = dst[e];
    const float4 v = *reinterpret_cast<const float4*>(H + (long)s * DIM + lane * 4);
    float* o = agg + (long)d * DIM + lane * 4;
    unsafeAtomicAdd(o + 0, v.x);
    unsafeAtomicAdd(o + 1, v.y);
    unsafeAtomicAdd(o + 2, v.z);
    unsafeAtomicAdd(o + 3, v.w);
}

__global__ void layer_mm(const float* __restrict__ agg, float* __restrict__ H,
                         const float* __restrict__ Wgc, const float* __restrict__ bgc,
                         const float* __restrict__ Wres, const float* __restrict__ bres) {
    __shared__ float sA[8][DIM];
    __shared__ float sH[8][DIM];
    const int tid = threadIdx.x;
    const long rowBase = (long)blockIdx.x * 8;
    const int r = tid >> 5;
    const int c = (tid & 31) * 4;
    *reinterpret_cast<float4*>(&sA[r][c]) =
        *reinterpret_cast<const float4*>(agg + (rowBase + r) * DIM + c);
    *reinterpret_cast<float4*>(&sH[r][c]) =
        *reinterpret_cast<const float4*>(H + (rowBase + r) * DIM + c);
    __syncthreads();
    float4 a1 = make_float4(0.f, 0.f, 0.f, 0.f);
    float4 a2 = make_float4(0.f, 0.f, 0.f, 0.f);
    #pragma unroll 8
    for (int k = 0; k < DIM; ++k) {
        const float av = sA[r][k];
        const float hv = sH[r][k];
        const float4 wg = *reinterpret_cast<const float4*>(Wgc + k * DIM + c);
        const float4 wr = *reinterpret_cast<const float4*>(Wres + k * DIM + c);
        a1.x += av * wg.x; a1.y += av * wg.y; a1.z += av * wg.z; a1.w += av * wg.w;
        a2.x += hv * wr.x; a2.y += hv * wr.y; a2.z += hv * wr.z; a2.w += hv * wr.w;
    }
    const float4 bg = *reinterpret_cast<const float4*>(bgc + c);
    const float4 br = *reinterpret_cast<const float4*>(bres + c);
    float4 o;
    o.x = fmaxf(a1.x + bg.x, 0.f) + fmaxf(a2.x + br.x, 0.f);
    o.y = fmaxf(a1.y + bg.y, 0.f) + fmaxf(a2.y + br.y, 0.f);
    o.z = fmaxf(a1.z + bg.z, 0.f) + fmaxf(a2.z + br.z, 0.f);
    o.w = fmaxf(a1.w + bg.w, 0.f) + fmaxf(a2.w + br.w, 0.f);
    *reinterpret_cast<float4*>(H + (rowBase + r) * DIM + c) = o;
}

// ================================================================ launch
extern "C" void kernel_launch(void* const* d_in, const int* in_sizes, int n_in,
                              void* d_out, int out_size, void* d_ws, size_t ws_size,
                              hipStream_t stream) {
    const float* node_feats = (const float*)d_in[0];
    const int*   src        = (const int*)d_in[1];
    const int*   dst        = (const int*)d_in[2];
    const float* W_init     = (const float*)d_in[3];
    const float* W_gc       = (const float*)d_in[4];
    const float* b_gc       = (const float*)d_in[5];
    const float* W_res      = (const float*)d_in[6];
    const float* b_res      = (const float*)d_in[7];

    const size_t HB_BYTES  = (size_t)N_NODES * DIM * sizeof(unsigned short);
    const size_t RP_BYTES  = ((size_t)(N_NODES + 1) * 4 + 255) & ~255ull;
    const size_t DEG_BYTES = ((size_t)N_NODES * 4 + 255) & ~255ull;
    const size_t CUR_BYTES = DEG_BYTES;
    const size_t BS_BYTES  = (((size_t)(N_NODES / 256)) * 4 + 255) & ~255ull;
    const size_t EIDX_BYTES = (size_t)N_EDGES * 4;
    const size_t NEED = 2 * HB_BYTES + RP_BYTES + DEG_BYTES + CUR_BYTES + BS_BYTES + EIDX_BYTES;

    if (ws_size >= NEED) {
        char* w = (char*)d_ws;
        unsigned short* Ha = (unsigned short*)w;      w += HB_BYTES;
        unsigned short* Hb = (unsigned short*)w;      w += HB_BYTES;
        int* rowptr = (int*)w;                        w += RP_BYTES;
        int* small  = (int*)w;                        w += DEG_BYTES;
        int* wtarea = (int*)w;                        w += CUR_BYTES;
        w += BS_BYTES;
        int* eidx   = (int*)w;

        int* ccnt       = small;                 // [NCHUNK]
        int* bcur       = small + NCHUNK;        // [NCHUNK]
        int* bucketBase = small + 2 * NCHUNK;    // [NCHUNK+1]
        unsigned int* bedge = (unsigned int*)Hb;
        unsigned short* Wt  = (unsigned short*)wtarea;
        unsigned short* WtI = Wt + 6 * 16384;
        float* Hout = (float*)d_out;

        zero_i<<<(2 * NCHUNK + 255) / 256, 256, 0, stream>>>(small, 2 * NCHUNK);
        coarse_hist<<<EBLKS, 256, 0, stream>>>(dst, ccnt);
        coarse_scan<<<1, NCHUNK, 0, stream>>>(ccnt, bucketBase);
        bucket_pass<<<EBLKS, 256, 0, stream>>>(src, dst, bucketBase, bcur, bedge);
        csr_pass<<<NCHUNK, 512, 0, stream>>>(bedge, bucketBase, rowptr, eidx);

        wcvt_all<<<384 + (128 * KUSE + 255) / 256, 256, 0, stream>>>(W_gc, W_res, W_init, Wt, WtI);
        init_mfma<<<N_NODES / 32, 256, 0, stream>>>(node_feats, WtI, Ha);

        layer_mfma<0><<<N_NODES / 32, 256, 0, stream>>>(
            Ha, Hb, nullptr, rowptr, eidx, Wt + 0 * 16384, Wt + 3 * 16384, b_gc, b_res);
        layer_mfma<0><<<N_NODES / 32, 256, 0, stream>>>(
            Hb, Ha, nullptr, rowptr, eidx, Wt + 1 * 16384, Wt + 4 * 16384,
            b_gc + DIM, b_res + DIM);
        layer_mfma<1><<<N_NODES / 32, 256, 0, stream>>>(
            Ha, nullptr, Hout, rowptr, eidx, Wt + 2 * 16384, Wt + 5 * 16384,
            b_gc + 2 * DIM, b_res + 2 * DIM);
    } else {
        float* H   = (float*)d_out;
        float* agg = (float*)d_ws;
        const int n4 = N_NODES * DIM / 4;
        init_mm<<<N_NODES / 8, 256, 0, stream>>>(node_feats, W_init, H);
        for (int l = 0; l < N_LAYERS; ++l) {
            zero_f4<<<(n4 + 255) / 256, 256, 0, stream>>>((float4*)agg, n4);
            scatter_add<<<(N_EDGES * 32) / 256, 256, 0, stream>>>(H, src, dst, agg);
            layer_mm<<<N_NODES / 8, 256, 0, stream>>>(agg, H,
                W_gc + (size_t)l * DIM * DIM, b_gc + (size_t)l * DIM,
                W_res + (size_t)l * DIM * DIM, b_res + (size_t)l * DIM);
        }
    }
}